// Round 2
// baseline (1213.878 us; speedup 1.0000x reference)
//
#include <hip/hip_runtime.h>

// Dtype theory (R2): reference is pure float32; harness contract maps inputs/output
// to f32 pointers. R1's NaN = f32 storage read as bf16 (mantissa bits decode as
// bf16 NaN/Inf). R0's absmax=454 vs zeroed out => max|ref|~454 => threshold 1.93e-2
// is ~4e-5 relative => internal math must be f32 (no fp32 MFMA on CDNA4 -> vector ALU).

typedef float f32x4 __attribute__((ext_vector_type(4)));
typedef float f32x2 __attribute__((ext_vector_type(2)));

#define B_   16
#define D_   192
#define T_   4096
#define BANK 1000
#define SP   1024            // bank padded to 32*32 chunks
#define DK   96
#define SCALE 0.10206207261596577f   // 1/sqrt(96)

// ---------------- K/V projection (tiny: 147 MFLOP) ----------------
// kws: [h][96 i][1024 s]  (s-contig rows: score-phase K staging reads b128 along s)
// vws: [h][1024 s][96 i]  (i-contig rows: PV staging is a flat contiguous copy)
__global__ __launch_bounds__(256) void kv_kernel(
    const float* __restrict__ mb, const float* __restrict__ Wk, const float* __restrict__ bk,
    const float* __restrict__ Wv, const float* __restrict__ bv,
    float* __restrict__ kws, float* __restrict__ vws) {
  int s = blockIdx.x * 256 + threadIdx.x;   // 0..1023
  int o = blockIdx.y;                       // 0..191
  int h = o / DK, i = o % DK;
  float ak = 0.f, av = 0.f;
  if (s < BANK) {
    ak = bk[o]; av = bv[o];
    for (int c = 0; c < D_; ++c) {
      float m = mb[c * BANK + s];           // coalesced across s
      ak += Wk[o * D_ + c] * m;             // broadcast
      av += Wv[o * D_ + c] * m;
    }
  }
  kws[(h * DK + i) * SP + s] = ak;          // pad rows s>=1000 get 0 (masked later anyway)
  vws[(h * SP + s) * DK + i] = av;
}

// ---------------- 1x1-conv projection: Y[b][o][t] = W X + bias ----------------
// Block: [64 o][64 t], 256 thr = 16 o_thr x 16 t_thr, per-thread 4o x 4t.
// c staged in chunks of 32: sW transposed [c'][o'], sX [c'][t']. Stride 68 floats:
// 16B-aligned rows, ~2-way max bank aliasing (free per m136).
#define PSW 68
__global__ __launch_bounds__(256) void proj_kernel(
    const float* __restrict__ X, const float* __restrict__ W,
    const float* __restrict__ bias, float* __restrict__ Y) {
  __shared__ __align__(16) float sW[32 * PSW];
  __shared__ __align__(16) float sX[32 * PSW];
  const int tid = threadIdx.x;
  const int t0 = blockIdx.x * 64, o0 = blockIdx.y * 64, b = blockIdx.z;
  const int o_thr = tid >> 4, t_thr = tid & 15;
  float acc[4][4] = {};
  for (int c0 = 0; c0 < D_; c0 += 32) {
    __syncthreads();
#pragma unroll
    for (int r = 0; r < 2; ++r) {           // W^T stage: 512 f32x4
      int idx = tid + 256 * r;
      int op = idx >> 3, c4 = idx & 7;
      f32x4 w = *(const f32x4*)&W[(o0 + op) * D_ + c0 + 4 * c4];
#pragma unroll
      for (int u = 0; u < 4; ++u) sW[(4 * c4 + u) * PSW + op] = w[u];
    }
#pragma unroll
    for (int r = 0; r < 2; ++r) {           // X stage: 512 f32x4, coalesced
      int idx = tid + 256 * r;
      int cp = idx >> 4, t4 = idx & 15;
      *(f32x4*)&sX[cp * PSW + 4 * t4] =
          *(const f32x4*)&X[((size_t)b * D_ + c0 + cp) * T_ + t0 + 4 * t4];
    }
    __syncthreads();
    for (int cp = 0; cp < 32; ++cp) {
      f32x4 w4 = *(const f32x4*)&sW[cp * PSW + 4 * o_thr];   // 4-addr broadcast
      f32x4 x4 = *(const f32x4*)&sX[cp * PSW + 4 * t_thr];   // 2-way (free)
#pragma unroll
      for (int j = 0; j < 4; ++j)
#pragma unroll
        for (int a = 0; a < 4; ++a) acc[j][a] += w4[j] * x4[a];
    }
  }
#pragma unroll
  for (int j = 0; j < 4; ++j) {
    float bb = bias[o0 + 4 * o_thr + j];
    f32x4 y;
#pragma unroll
    for (int a = 0; a < 4; ++a) y[a] = acc[j][a] + bb;
    *(f32x4*)&Y[((size_t)b * D_ + o0 + 4 * o_thr + j) * T_ + t0 + 4 * t_thr] = y;
  }
}

// ---------------- flash attention, f32, online softmax ----------------
// Block = (b, h, 64 t). 256 thr. s-chunks of 32. Score role: 16 t_thr(x4t) x 16 s_thr(x2s).
// PV role: 16 t_thr(x4t) x 16 i_thr(x6i). m/l/alpha per t-row live in LDS; only s_thr==0
// writes them (reads of sM by all lanes precede the write in wave program order).
__global__ __launch_bounds__(256) void attn_kernel(
    const float* __restrict__ qws, const float* __restrict__ kws,
    const float* __restrict__ vws, float* __restrict__ ows) {
  __shared__ __align__(16) float sQ[96 * 64];   // [i][t]   24 KB
  __shared__ __align__(16) float sK[96 * 32];   // [i][s']  12 KB
  __shared__ __align__(16) float sV[32 * 96];   // [s'][i]  12 KB
  __shared__ __align__(16) float sP[32 * 68];   // [s'][t]  8.5 KB (stride 68: aligned + low conflict)
  __shared__ __align__(16) float sM[64], sL[64], sAl[64];

  const int tid = threadIdx.x;
  const int t0 = blockIdx.x * 64, h = blockIdx.y, b = blockIdx.z;
  const int s_thr = tid & 15;    // also i_thr in PV phase
  const int t_thr = tid >> 4;

  const float* qbase = qws + ((size_t)(b * D_ + h * DK)) * T_ + t0;
  const float* kb = kws + (size_t)h * DK * SP;
  const float* vb = vws + (size_t)h * SP * DK;

#pragma unroll
  for (int r = 0; r < 6; ++r) {              // stage Q tile [96][64]
    int idx = tid + 256 * r;
    int row = idx >> 4, c4 = idx & 15;
    *(f32x4*)&sQ[row * 64 + 4 * c4] = *(const f32x4*)&qbase[(size_t)row * T_ + 4 * c4];
  }
  if (tid < 64) { sM[tid] = -1e30f; sL[tid] = 0.f; }

  float o_acc[4][6] = {};

  for (int ch = 0; ch < 32; ++ch) {
    const int s0 = ch * 32;
    __syncthreads();                          // (A) prev PV readers done before re-stage
#pragma unroll
    for (int r = 0; r < 3; ++r) {             // stage K chunk [96][32]
      int idx = tid + 256 * r;
      int row = idx >> 3, c4 = idx & 7;
      *(f32x4*)&sK[row * 32 + 4 * c4] = *(const f32x4*)&kb[(size_t)row * SP + s0 + 4 * c4];
    }
#pragma unroll
    for (int r = 0; r < 3; ++r) {             // stage V chunk [32][96] (flat copy)
      int idx = tid + 256 * r;
      *(f32x4*)&sV[idx * 4] = *(const f32x4*)&vb[(size_t)s0 * DK + idx * 4];
    }
    __syncthreads();                          // (B)

    // ---- scores: 4t x 2s dots over 96 ----
    float Sv[4][2] = {};
    for (int i = 0; i < DK; ++i) {
      f32x4 q4 = *(const f32x4*)&sQ[i * 64 + 4 * t_thr];
      f32x2 k2 = *(const f32x2*)&sK[i * 32 + 2 * s_thr];
#pragma unroll
      for (int a = 0; a < 4; ++a) {
        Sv[a][0] += q4[a] * k2[0];
        Sv[a][1] += q4[a] * k2[1];
      }
    }
#pragma unroll
    for (int c = 0; c < 2; ++c)
      if (s0 + 2 * s_thr + c >= BANK)
#pragma unroll
        for (int a = 0; a < 4; ++a) Sv[a][c] = -1e30f;

    float mc[4];
#pragma unroll
    for (int a = 0; a < 4; ++a) mc[a] = fmaxf(Sv[a][0], Sv[a][1]);
#pragma unroll
    for (int d = 1; d < 16; d <<= 1)
#pragma unroll
      for (int a = 0; a < 4; ++a) mc[a] = fmaxf(mc[a], __shfl_xor(mc[a], d, 16));

    f32x4 mo = *(const f32x4*)&sM[4 * t_thr];  // read precedes writer's store (same wave)
    float mn[4], p[4][2], ls[4];
#pragma unroll
    for (int a = 0; a < 4; ++a) {
      mn[a] = fmaxf(mo[a], mc[a]);
      p[a][0] = __expf((Sv[a][0] - mn[a]) * SCALE);   // masked -> exp(-1e29) = 0
      p[a][1] = __expf((Sv[a][1] - mn[a]) * SCALE);
      ls[a] = p[a][0] + p[a][1];
    }
#pragma unroll
    for (int d = 1; d < 16; d <<= 1)
#pragma unroll
      for (int a = 0; a < 4; ++a) ls[a] += __shfl_xor(ls[a], d, 16);
#pragma unroll
    for (int c = 0; c < 2; ++c)
#pragma unroll
      for (int a = 0; a < 4; ++a)
        sP[(2 * s_thr + c) * 68 + 4 * t_thr + a] = p[a][c];
    if (s_thr == 0) {
#pragma unroll
      for (int a = 0; a < 4; ++a) {
        int t = 4 * t_thr + a;
        float al = __expf((mo[a] - mn[a]) * SCALE);   // first chunk: exp(-1e29)=0
        sAl[t] = al;
        sM[t] = mn[a];
        sL[t] = sL[t] * al + ls[a];
      }
    }
    __syncthreads();                          // (C)

    // ---- PV: 4t x 6i ----
    f32x4 al4 = *(const f32x4*)&sAl[4 * t_thr];
#pragma unroll
    for (int a = 0; a < 4; ++a)
#pragma unroll
      for (int k = 0; k < 6; ++k) o_acc[a][k] *= al4[a];
    for (int s = 0; s < 32; ++s) {
      f32x4 p4 = *(const f32x4*)&sP[s * 68 + 4 * t_thr];
      f32x2 v0 = *(const f32x2*)&sV[s * 96 + 6 * s_thr + 0];
      f32x2 v1 = *(const f32x2*)&sV[s * 96 + 6 * s_thr + 2];
      f32x2 v2 = *(const f32x2*)&sV[s * 96 + 6 * s_thr + 4];
#pragma unroll
      for (int a = 0; a < 4; ++a) {
        o_acc[a][0] += p4[a] * v0[0];  o_acc[a][1] += p4[a] * v0[1];
        o_acc[a][2] += p4[a] * v1[0];  o_acc[a][3] += p4[a] * v1[1];
        o_acc[a][4] += p4[a] * v2[0];  o_acc[a][5] += p4[a] * v2[1];
      }
    }
  }

  f32x4 l4 = *(const f32x4*)&sL[4 * t_thr];
  float inv[4];
#pragma unroll
  for (int a = 0; a < 4; ++a) inv[a] = 1.0f / l4[a];
  size_t obase = ((size_t)(b * D_ + h * DK)) * T_ + t0;
#pragma unroll
  for (int k = 0; k < 6; ++k) {
    int i = 6 * s_thr + k;
    f32x4 y;
#pragma unroll
    for (int a = 0; a < 4; ++a) y[a] = o_acc[a][k] * inv[a];
    *(f32x4*)&ows[obase + (size_t)i * T_ + 4 * t_thr] = y;
  }
}

extern "C" void kernel_launch(void* const* d_in, const int* in_sizes, int n_in,
                              void* d_out, int out_size, void* d_ws, size_t ws_size,
                              hipStream_t stream) {
  const float* z  = (const float*)d_in[0];
  const float* mb = (const float*)d_in[1];
  const float* Wq = (const float*)d_in[2];
  const float* bq = (const float*)d_in[3];
  const float* Wk = (const float*)d_in[4];
  const float* bk = (const float*)d_in[5];
  const float* Wv = (const float*)d_in[6];
  const float* bv = (const float*)d_in[7];
  const float* Wo = (const float*)d_in[8];
  const float* bo = (const float*)d_in[9];
  float* out = (float*)d_out;

  // ws (f32): kws 2*96*1024 | vws 2*1024*96 | qws 16*192*4096 | ows 16*192*4096
  // total 25,559,040 floats = 102.2 MB
  float* kws = (float*)d_ws;
  float* vws = kws + 2 * DK * SP;
  float* qws = vws + 2 * SP * DK;
  float* ows = qws + (size_t)B_ * D_ * T_;

  kv_kernel  <<<dim3(SP / 256, D_),        256, 0, stream>>>(mb, Wk, bk, Wv, bv, kws, vws);
  proj_kernel<<<dim3(T_ / 64, 3, B_),      256, 0, stream>>>(z, Wq, bq, qws);
  attn_kernel<<<dim3(T_ / 64, 2, B_),      256, 0, stream>>>(qws, kws, vws, ows);
  proj_kernel<<<dim3(T_ / 64, 3, B_),      256, 0, stream>>>(ows, Wo, bo, out);
}